// Round 6
// baseline (2185.486 us; speedup 1.0000x reference)
//
#include <hip/hip_runtime.h>
#include <math.h>

// Problem dims
#define N_ 4
#define C_ 512
#define L_ 4096
#define D_ 256
#define K_ 8192
#define NL_ 16384           // N_*L_

// d_out layout (float32 flat): y | code_index(as float) | cb_loss | cm_loss
#define OUT_IDX_OFF (N_*C_*L_)          // 8388608
#define OUT_CB_OFF  (OUT_IDX_OFF + NL_) // 8404992

// ws layout (float units). Total ~19.2M floats ~= 77 MB.
#define WS_ZT   0                                  // Zt[16384][256] f32
#define WS_P    (WS_ZT + (size_t)NL_*D_)           // P[8192][512] f32
#define WS_Z2   (WS_P + (size_t)K_*C_)             // Z2[16384][512] bf16 (hi|lo)
#define WS_CB2  (WS_Z2 + (size_t)NL_*D_)           // CB2[8192][512] bf16 (hi|lo, invn folded)
#define WS_PART (WS_CB2 + (size_t)K_*D_)           // Part[16384][64][4] f32 top2 partials
#define WS_WIN  (WS_PART + (size_t)NL_*64*4)       // W_in[256][512]
#define WS_WOUT (WS_WIN + (size_t)D_*C_)           // W_out[512][256]
#define WS_INVN (WS_WOUT + (size_t)C_*D_)          // inv codebook norms [8192]
#define WS_IDX  (WS_INVN + (size_t)K_)             // idx[16384] (int)
#define WS_LOSS (WS_IDX + (size_t)NL_)             // loss accum [4]

typedef __bf16 bf16x8 __attribute__((ext_vector_type(8)));
typedef float  f32x4  __attribute__((ext_vector_type(4)));
typedef unsigned int u32;

__device__ __forceinline__ unsigned short f2bf(float f) {   // round-nearest-even
    u32 u = __float_as_uint(f);
    u32 r = (u + 0x7fffu + ((u >> 16) & 1u)) >> 16;
    return (unsigned short)r;
}
__device__ __forceinline__ float bf2f(unsigned short h) {
    return __uint_as_float(((u32)h) << 16);
}

__device__ __forceinline__ float waveReduceSum64(float s) {
    #pragma unroll
    for (int off = 32; off; off >>= 1) s += __shfl_xor(s, off, 64);
    return s;
}

// prefer (av,ai) over (bv,bi)?  larger value wins; tie -> smaller index
__device__ __forceinline__ bool pref(float av, int ai, float bv, int bi) {
    return (av > bv) || (av == bv && ai < bi);
}
// push candidate (wv,wi) into sorted top2 (v1,i1,v2,i2)
__device__ __forceinline__ void push2(float& v1, int& i1, float& v2, int& i2,
                                      float wv, int wi) {
    if (pref(wv, wi, v1, i1)) { v2 = v1; i2 = i1; v1 = wv; i1 = wi; }
    else if (pref(wv, wi, v2, i2)) { v2 = wv; i2 = wi; }
}

// ---------------------------------------------------------------------------
// prep: W_in = g*v/||v||, W_out likewise, zero loss accum.
// ---------------------------------------------------------------------------
__global__ __launch_bounds__(64) void prep_kernel(
    const float* __restrict__ in_v, const float* __restrict__ in_g,
    const float* __restrict__ out_v, const float* __restrict__ out_g,
    float* __restrict__ Win, float* __restrict__ Wout,
    float* __restrict__ lossacc)
{
    const int b = blockIdx.x;
    const int t = threadIdx.x;
    if (b == 0 && t < N_) lossacc[t] = 0.0f;
    if (b < D_) {
        const float* v = in_v + (size_t)b * C_;
        float4 a0 = *(const float4*)(v + t * 4);
        float4 a1 = *(const float4*)(v + 256 + t * 4);
        float s = a0.x*a0.x + a0.y*a0.y + a0.z*a0.z + a0.w*a0.w
                + a1.x*a1.x + a1.y*a1.y + a1.z*a1.z + a1.w*a1.w;
        s = waveReduceSum64(s);
        float scale = in_g[b] / sqrtf(s);
        float* w = Win + (size_t)b * C_;
        float4 o0, o1;
        o0.x=a0.x*scale; o0.y=a0.y*scale; o0.z=a0.z*scale; o0.w=a0.w*scale;
        o1.x=a1.x*scale; o1.y=a1.y*scale; o1.z=a1.z*scale; o1.w=a1.w*scale;
        *(float4*)(w + t*4) = o0;
        *(float4*)(w + 256 + t*4) = o1;
    } else {
        const int r = b - D_;
        const float* v = out_v + (size_t)r * D_;
        float4 a0 = *(const float4*)(v + t * 4);
        float s = a0.x*a0.x + a0.y*a0.y + a0.z*a0.z + a0.w*a0.w;
        s = waveReduceSum64(s);
        float scale = out_g[r] / sqrtf(s);
        float4 o0;
        o0.x=a0.x*scale; o0.y=a0.y*scale; o0.z=a0.z*scale; o0.w=a0.w*scale;
        *(float4*)(Wout + (size_t)r * D_ + t*4) = o0;
    }
}

// ---------------------------------------------------------------------------
// cb2: invn[k] = 1/max(||cb_k||,eps); CB2[k] = [hi(cb_k*invn) | lo(cb_k*invn)]
// grid 8192 x 64
// ---------------------------------------------------------------------------
__global__ __launch_bounds__(64) void cb2_kernel(
    const float* __restrict__ cb, unsigned short* __restrict__ CB2,
    float* __restrict__ invn)
{
    const int k = blockIdx.x;
    const int t = threadIdx.x;
    float4 v = *(const float4*)(cb + (size_t)k * D_ + t * 4);
    float s = v.x*v.x + v.y*v.y + v.z*v.z + v.w*v.w;
    s = waveReduceSum64(s);
    float inv = 1.0f / fmaxf(sqrtf(s), 1e-8f);
    if (t == 0) invn[k] = inv;
    float c0 = v.x*inv, c1 = v.y*inv, c2 = v.z*inv, c3 = v.w*inv;
    ushort4 h, lo;
    h.x = f2bf(c0); h.y = f2bf(c1); h.z = f2bf(c2); h.w = f2bf(c3);
    lo.x = f2bf(c0 - bf2f(h.x)); lo.y = f2bf(c1 - bf2f(h.y));
    lo.z = f2bf(c2 - bf2f(h.z)); lo.w = f2bf(c3 - bf2f(h.w));
    *(ushort4*)&CB2[(size_t)k * 512 + t*4]       = h;
    *(ushort4*)&CB2[(size_t)k * 512 + 256 + t*4] = lo;
}

// ---------------------------------------------------------------------------
// z_e GEMM: Zt[n*L+l][d] = sum_c x[n][c][l]*Win[d][c] + in_b[d]; also writes
// bf16 split Z2[row] = [hi | lo].
// ---------------------------------------------------------------------------
__global__ __launch_bounds__(256) void ze_kernel(
    const float* __restrict__ x, const float* __restrict__ Win,
    const float* __restrict__ inb, float* __restrict__ Zt,
    unsigned short* __restrict__ Z2)
{
    __shared__ float Al[2][16][64];   // x tile [c][l]
    __shared__ float Bl[2][16][68];   // Win tile [c][d] (padded)
    const int tid = threadIdx.x;
    const int ty = tid >> 4, tx = tid & 15;
    const int l0 = blockIdx.x * 64;
    const int d0 = blockIdx.y * 64;
    const int n  = blockIdx.z;
    const float* xn = x + (size_t)n * C_ * L_;

    const int ac = tid >> 4, alq = tid & 15;
    const int bd = tid >> 2, bq  = tid & 3;

    float acc[4][4];
    #pragma unroll
    for (int i = 0; i < 4; ++i)
        #pragma unroll
        for (int j = 0; j < 4; ++j) acc[i][j] = 0.0f;

    auto stage = [&](int cc, int buf) {
        float4 av = *(const float4*)(xn + (size_t)(cc*16 + ac) * L_ + l0 + alq*4);
        *(float4*)&Al[buf][ac][alq*4] = av;
        float4 bv = *(const float4*)(Win + (size_t)(d0 + bd) * C_ + cc*16 + bq*4);
        Bl[buf][bq*4+0][bd] = bv.x; Bl[buf][bq*4+1][bd] = bv.y;
        Bl[buf][bq*4+2][bd] = bv.z; Bl[buf][bq*4+3][bd] = bv.w;
    };

    stage(0, 0);
    for (int cc = 0; cc < 32; ++cc) {
        __syncthreads();
        if (cc + 1 < 32) stage(cc + 1, (cc + 1) & 1);
        const int buf = cc & 1;
        #pragma unroll
        for (int k = 0; k < 16; ++k) {
            float4 a = *(const float4*)&Al[buf][k][ty*4];
            float4 b = *(const float4*)&Bl[buf][k][tx*4];
            acc[0][0]=fmaf(a.x,b.x,acc[0][0]); acc[0][1]=fmaf(a.x,b.y,acc[0][1]);
            acc[0][2]=fmaf(a.x,b.z,acc[0][2]); acc[0][3]=fmaf(a.x,b.w,acc[0][3]);
            acc[1][0]=fmaf(a.y,b.x,acc[1][0]); acc[1][1]=fmaf(a.y,b.y,acc[1][1]);
            acc[1][2]=fmaf(a.y,b.z,acc[1][2]); acc[1][3]=fmaf(a.y,b.w,acc[1][3]);
            acc[2][0]=fmaf(a.z,b.x,acc[2][0]); acc[2][1]=fmaf(a.z,b.y,acc[2][1]);
            acc[2][2]=fmaf(a.z,b.z,acc[2][2]); acc[2][3]=fmaf(a.z,b.w,acc[2][3]);
            acc[3][0]=fmaf(a.w,b.x,acc[3][0]); acc[3][1]=fmaf(a.w,b.y,acc[3][1]);
            acc[3][2]=fmaf(a.w,b.z,acc[3][2]); acc[3][3]=fmaf(a.w,b.w,acc[3][3]);
        }
    }
    float4 bias = *(const float4*)(inb + d0 + tx*4);
    #pragma unroll
    for (int i = 0; i < 4; ++i) {
        float4 o;
        o.x = acc[i][0] + bias.x; o.y = acc[i][1] + bias.y;
        o.z = acc[i][2] + bias.z; o.w = acc[i][3] + bias.w;
        const size_t row = (size_t)(n*L_ + l0 + ty*4 + i);
        *(float4*)&Zt[row * D_ + d0 + tx*4] = o;
        ushort4 h, lo;
        h.x = f2bf(o.x); h.y = f2bf(o.y); h.z = f2bf(o.z); h.w = f2bf(o.w);
        lo.x = f2bf(o.x - bf2f(h.x)); lo.y = f2bf(o.y - bf2f(h.y));
        lo.z = f2bf(o.z - bf2f(h.z)); lo.w = f2bf(o.w - bf2f(h.w));
        *(ushort4*)&Z2[row * 512 + d0 + tx*4]       = h;
        *(ushort4*)&Z2[row * 512 + 256 + d0 + tx*4] = lo;
    }
}

// ---------------------------------------------------------------------------
// P GEMM: P[k][c] = sum_d cb[k][d] * Wout[c][d]    (8192 x 512 x 256)
// ---------------------------------------------------------------------------
__global__ __launch_bounds__(256) void pmat_kernel(
    const float* __restrict__ cb, const float* __restrict__ Wout,
    float* __restrict__ P)
{
    __shared__ float Al[2][16][68];
    __shared__ float Bl[2][16][68];
    const int tid = threadIdx.x;
    const int ty = tid >> 4, tx = tid & 15;
    const int k0 = blockIdx.x * 64;
    const int c0 = blockIdx.y * 64;
    const int ar = tid >> 2, aq = tid & 3;

    float acc[4][4];
    #pragma unroll
    for (int i = 0; i < 4; ++i)
        #pragma unroll
        for (int j = 0; j < 4; ++j) acc[i][j] = 0.0f;

    auto stage = [&](int dc, int buf) {
        float4 av = *(const float4*)(cb + (size_t)(k0 + ar) * D_ + dc*16 + aq*4);
        Al[buf][aq*4+0][ar] = av.x; Al[buf][aq*4+1][ar] = av.y;
        Al[buf][aq*4+2][ar] = av.z; Al[buf][aq*4+3][ar] = av.w;
        float4 bv = *(const float4*)(Wout + (size_t)(c0 + ar) * D_ + dc*16 + aq*4);
        Bl[buf][aq*4+0][ar] = bv.x; Bl[buf][aq*4+1][ar] = bv.y;
        Bl[buf][aq*4+2][ar] = bv.z; Bl[buf][aq*4+3][ar] = bv.w;
    };

    stage(0, 0);
    for (int dc = 0; dc < 16; ++dc) {
        __syncthreads();
        if (dc + 1 < 16) stage(dc + 1, (dc + 1) & 1);
        const int buf = dc & 1;
        #pragma unroll
        for (int k = 0; k < 16; ++k) {
            float4 a = *(const float4*)&Al[buf][k][ty*4];
            float4 b = *(const float4*)&Bl[buf][k][tx*4];
            acc[0][0]=fmaf(a.x,b.x,acc[0][0]); acc[0][1]=fmaf(a.x,b.y,acc[0][1]);
            acc[0][2]=fmaf(a.x,b.z,acc[0][2]); acc[0][3]=fmaf(a.x,b.w,acc[0][3]);
            acc[1][0]=fmaf(a.y,b.x,acc[1][0]); acc[1][1]=fmaf(a.y,b.y,acc[1][1]);
            acc[1][2]=fmaf(a.y,b.z,acc[1][2]); acc[1][3]=fmaf(a.y,b.w,acc[1][3]);
            acc[2][0]=fmaf(a.z,b.x,acc[2][0]); acc[2][1]=fmaf(a.z,b.y,acc[2][1]);
            acc[2][2]=fmaf(a.z,b.z,acc[2][2]); acc[2][3]=fmaf(a.z,b.w,acc[2][3]);
            acc[3][0]=fmaf(a.w,b.x,acc[3][0]); acc[3][1]=fmaf(a.w,b.y,acc[3][1]);
            acc[3][2]=fmaf(a.w,b.z,acc[3][2]); acc[3][3]=fmaf(a.w,b.w,acc[3][3]);
        }
    }
    #pragma unroll
    for (int i = 0; i < 4; ++i) {
        float4 o;
        o.x = acc[i][0]; o.y = acc[i][1]; o.z = acc[i][2]; o.w = acc[i][3];
        *(float4*)&P[(size_t)(k0 + ty*4 + i) * C_ + c0 + tx*4] = o;
    }
}

// ---------------------------------------------------------------------------
// sim (MFMA): 3-term bf16-split GEMM, K=768 = 12 slabs of BK=64.
// MECHANISM-ISOLATION rewrite: NO global_load_lds.  Register staging:
//   prologue: global loads slab 0 -> VGPRs
//   for ks: { barrier (readers of slab ks-1 done);
//             ds_write_b128 slab ks from VGPRs;
//             issue global loads slab ks+1 -> VGPRs (in flight across compute,
//               never drained by a barrier);
//             barrier (LDS visible);  compute slab ks }
// Single 32 KB LDS buffer, XOR-swizzled 16B chunks (LDS row r, chunk c holds
// logical chunk c^(r&7)) -> conflict-free frag reads (proven round 5); global
// loads are contiguous 64 B per thread (swizzle applied on LDS side).
// XCD locality mapping + epilogue identical to round 5.  grid 8192 x 256.
// ---------------------------------------------------------------------------
__global__ __launch_bounds__(256, 3) void sim_kernel(
    const unsigned short* __restrict__ Z2, const unsigned short* __restrict__ CB2,
    float* __restrict__ Part)
{
    __shared__ unsigned short Asm[128][64];   // [m][k] bf16, swizzled, 16 KB
    __shared__ unsigned short Bsm[128][64];   // [n][k] bf16, swizzled, 16 KB

    const int tid = threadIdx.x;
    const int w   = tid >> 6;       // wave 0..3
    const int l   = tid & 63;
    const int qg  = l >> 4;         // quarter-group 0..3
    const int fr  = l & 15;         // fragment row

    // XCD-locality mapping (bid%8 -> XCD round-robin heuristic; perf-only)
    const int bid   = blockIdx.x;
    const int g     = bid >> 3;
    const int ntile = (bid & 7) * 8 + (g & 7);   // 0..63
    const int mtile = g >> 3;                    // 0..127
    const int m0 = mtile * 128, n0 = ntile * 128;

    const int wm = (w >> 1) * 64;   // wave m-offset in tile
    const int wn = (w & 1) * 64;    // wave n-offset in tile

    // staging: thread t covers row (t>>1), 64-B half (t&1) = 4 chunks of 16 B
    const int srow  = tid >> 1;
    const int scb   = (tid & 1) * 4;             // first logical chunk
    const char* Arow = (const char*)Z2  + (size_t)(m0 + srow) * 1024 + scb * 16;
    const char* Brow = (const char*)CB2 + (size_t)(n0 + srow) * 1024 + scb * 16;

    float4 areg[4], breg[4];
    auto gload = [&](int ks) {
        const int seg = ks >> 2;                 // 0,1,2
        const int hb  = (ks & 3) * 128;          // bytes within 512-B half
        const int aoff = ((seg == 1) ? 512 : 0) + hb;   // A: hi,lo,hi
        const int boff = ((seg == 2) ? 512 : 0) + hb;   // B: hi,hi,lo
        #pragma unroll
        for (int i = 0; i < 4; ++i) {
            areg[i] = *(const float4*)(Arow + aoff + i * 16);
            breg[i] = *(const float4*)(Brow + boff + i * 16);
        }
    };
    auto dswrite = [&]() {
        #pragma unroll
        for (int i = 0; i < 4; ++i) {
            const int c = ((scb + i) ^ (srow & 7)) * 8;   // swizzled chunk (shorts)
            *(float4*)&Asm[srow][c] = areg[i];
            *(float4*)&Bsm[srow][c] = breg[i];
        }
    };

    f32x4 acc[4][4];
    const f32x4 z4 = {0.0f, 0.0f, 0.0f, 0.0f};
    #pragma unroll
    for (int i = 0; i < 4; ++i)
        #pragma unroll
        for (int j = 0; j < 4; ++j) acc[i][j] = z4;

    gload(0);
    for (int ks = 0; ks < 12; ++ks) {
        __syncthreads();                 // readers of previous slab done
        dswrite();
        if (ks < 11) gload(ks + 1);      // in flight across compute phase
        __syncthreads();                 // slab ks visible in LDS
        #pragma unroll
        for (int kk = 0; kk < 2; ++kk) {
            bf16x8 af[4], bg[4];
            #pragma unroll
            for (int i = 0; i < 4; ++i) {
                const int r = wm + i*16 + fr;
                af[i] = *(const bf16x8*)&Asm[r][(((kk*4 + qg) ^ (r & 7)) * 8)];
            }
            #pragma unroll
            for (int j = 0; j < 4; ++j) {
                const int r = wn + j*16 + fr;
                bg[j] = *(const bf16x8*)&Bsm[r][(((kk*4 + qg) ^ (r & 7)) * 8)];
            }
            #pragma unroll
            for (int i = 0; i < 4; ++i)
                #pragma unroll
                for (int j = 0; j < 4; ++j)
                    acc[i][j] = __builtin_amdgcn_mfma_f32_16x16x32_bf16(
                        af[i], bg[j], acc[i][j], 0, 0, 0);
        }
    }

    __syncthreads();                           // all LDS reads done
    float* TopF = (float*)&Asm[0][0];          // overlay [2][128][4], 4 KB

    // epilogue: per-lane top2, merge across the 16 col-lanes, stash per n-half
    // C/D layout: col = lane&15, row = (lane>>4)*4 + reg
    const int colbase = n0 + wn + fr;          // + j*16
    #pragma unroll
    for (int i = 0; i < 4; ++i) {
        #pragma unroll
        for (int t = 0; t < 4; ++t) {
            float v1 = -3.0e38f, v2 = -3.0e38f;
            int   i1 = 0x7FFFFFFF, i2 = 0x7FFFFFFF;
            #pragma unroll
            for (int j = 0; j < 4; ++j)
                push2(v1, i1, v2, i2, acc[i][j][t], colbase + j*16);
            #pragma unroll
            for (int mask = 1; mask < 16; mask <<= 1) {
                float ov1 = __shfl_xor(v1, mask, 64);
                int   oi1 = __shfl_xor(i1, mask, 64);
                float ov2 = __shfl_xor(v2, mask, 64);
                int   oi2 = __shfl_xor(i2, mask, 64);
                push2(v1, i1, v2, i2, ov1, oi1);
                push2(v1, i1, v2, i2, ov2, oi2);
            }
            if (fr == 0) {
                const int rloc = wm + i*16 + qg*4 + t;
                float* tp = TopF + ((w & 1) * 128 + rloc) * 4;
                tp[0] = v1; tp[1] = __int_as_float(i1);
                tp[2] = v2; tp[3] = __int_as_float(i2);
            }
        }
    }
    __syncthreads();
    if (tid < 128) {
        const float* t0 = TopF + tid * 4;
        const float* t1 = TopF + (128 + tid) * 4;
        float v1 = t0[0], v2 = t0[2];
        int   i1 = __float_as_int(t0[1]), i2 = __float_as_int(t0[3]);
        push2(v1, i1, v2, i2, t1[0], __float_as_int(t1[1]));
        push2(v1, i1, v2, i2, t1[2], __float_as_int(t1[3]));
        float4 o;
        o.x = v1; o.y = __int_as_float(i1); o.z = v2; o.w = __int_as_float(i2);
        *(float4*)&Part[((size_t)(m0 + tid) * 64 + ntile) * 4] = o;
    }
}

// ---------------------------------------------------------------------------
// argmax reduce + exact fp32 recheck: merge 64 partials/row -> global top2,
// recompute both dots in fp32, pick winner (tie -> smaller index).
// grid 4096 x 256 (wave per row).
// ---------------------------------------------------------------------------
__global__ __launch_bounds__(256) void argmax_kernel(
    const float* __restrict__ Part, const float* __restrict__ Zt,
    const float* __restrict__ cb, const float* __restrict__ invn,
    int* __restrict__ idxout, float* __restrict__ fidxout)
{
    const int w = threadIdx.x >> 6, l = threadIdx.x & 63;
    const int row = blockIdx.x * 4 + w;
    float4 p = *(const float4*)&Part[((size_t)row * 64 + l) * 4];
    float v1 = p.x, v2 = p.z;
    int   i1 = __float_as_int(p.y), i2 = __float_as_int(p.w);
    #pragma unroll
    for (int mask = 1; mask < 64; mask <<= 1) {
        float ov1 = __shfl_xor(v1, mask, 64);
        int   oi1 = __shfl_xor(i1, mask, 64);
        float ov2 = __shfl_xor(v2, mask, 64);
        int   oi2 = __shfl_xor(i2, mask, 64);
        push2(v1, i1, v2, i2, ov1, oi1);
        push2(v1, i1, v2, i2, ov2, oi2);
    }
    // exact fp32 dots for the two candidates
    const float* z  = Zt + (size_t)row * D_;
    float4 zv = *(const float4*)(z + l*4);
    float4 a  = *(const float4*)(cb + (size_t)i1 * D_ + l*4);
    float4 b  = *(const float4*)(cb + (size_t)i2 * D_ + l*4);
    float s1 = zv.x*a.x + zv.y*a.y + zv.z*a.z + zv.w*a.w;
    float s2 = zv.x*b.x + zv.y*b.y + zv.z*b.z + zv.w*b.w;
    s1 = waveReduceSum64(s1);
    s2 = waveReduceSum64(s2);
    float e1 = s1 * invn[i1];
    float e2 = s2 * invn[i2];
    int win = (e2 > e1 || (e2 == e1 && i2 < i1)) ? i2 : i1;
    if (l == 0) { idxout[row] = win; fidxout[row] = (float)win; }
}

// ---------------------------------------------------------------------------
// losses: S[n] = sum_{l,d} (cb[idx[n,l]][d] - Zt[n*L+l][d])^2
// ---------------------------------------------------------------------------
__global__ __launch_bounds__(256) void loss_kernel(
    const float* __restrict__ Zt, const float* __restrict__ cb,
    const int* __restrict__ idx, float* __restrict__ lossacc)
{
    __shared__ float red[4];
    const int tid = threadIdx.x;
    const int r = blockIdx.x * 64 + (tid >> 2);
    const int q = tid & 3;
    const int n = r >> 12;
    const int code = idx[r];
    const float* zp = Zt + (size_t)r * D_ + q * 64;
    const float* cp = cb + (size_t)code * D_ + q * 64;
    float s = 0.0f;
    #pragma unroll
    for (int it = 0; it < 16; ++it) {
        float4 a = *(const float4*)(zp + it*4);
        float4 c = *(const float4*)(cp + it*4);
        float dx = c.x - a.x, dy = c.y - a.y, dz = c.z - a.z, dw = c.w - a.w;
        s += dx*dx + dy*dy + dz*dz + dw*dw;
    }
    s = waveReduceSum64(s);
    if ((tid & 63) == 0) red[tid >> 6] = s;
    __syncthreads();
    if (tid == 0) atomicAdd(&lossacc[n], red[0] + red[1] + red[2] + red[3]);
}

// ---------------------------------------------------------------------------
// y gather: y[n][c][l] = P[idx[n,l]][c] + out_b[c]
// ---------------------------------------------------------------------------
__global__ __launch_bounds__(256) void y_kernel(
    const float* __restrict__ P, const int* __restrict__ idx,
    const float* __restrict__ outb, float* __restrict__ y)
{
    __shared__ float bias[128];
    const int t = threadIdx.x;
    const int c0 = blockIdx.y * 128;
    const int n = blockIdx.z;
    const int l = blockIdx.x * 256 + t;
    if (t < 128) bias[t] = outb[c0 + t];
    __syncthreads();
    const int code = idx[n * L_ + l];
    const float* prow = P + (size_t)code * C_ + c0;
    float* yb = y + ((size_t)n * C_ + c0) * L_ + l;
    #pragma unroll 4
    for (int c = 0; c < 128; ++c) {
        yb[(size_t)c * L_] = prow[c] + bias[c];
    }
}

__global__ __launch_bounds__(64) void fin_kernel(
    const float* __restrict__ lossacc, float* __restrict__ out)
{
    const int t = threadIdx.x;
    if (t < 8) out[t] = lossacc[t & 3] * (1.0f / (float)(D_ * L_));
}

extern "C" void kernel_launch(void* const* d_in, const int* in_sizes, int n_in,
                              void* d_out, int out_size, void* d_ws, size_t ws_size,
                              hipStream_t stream) {
    (void)in_sizes; (void)n_in; (void)out_size; (void)ws_size;
    const float* x     = (const float*)d_in[0];
    const float* in_v  = (const float*)d_in[1];
    const float* in_g  = (const float*)d_in[2];
    const float* in_b  = (const float*)d_in[3];
    const float* out_v = (const float*)d_in[4];
    const float* out_g = (const float*)d_in[5];
    const float* out_b = (const float*)d_in[6];
    const float* cb    = (const float*)d_in[7];
    float* out = (float*)d_out;
    float* ws  = (float*)d_ws;

    float*          Zt     = ws + WS_ZT;
    float*          P      = ws + WS_P;
    unsigned short* Z2     = (unsigned short*)(ws + WS_Z2);
    unsigned short* CB2    = (unsigned short*)(ws + WS_CB2);
    float*          Part   = ws + WS_PART;
    float*          Win    = ws + WS_WIN;
    float*          Wout   = ws + WS_WOUT;
    float*          invn   = ws + WS_INVN;
    int*            idx    = (int*)(ws + WS_IDX);
    float*          lossac = ws + WS_LOSS;

    prep_kernel<<<dim3(D_ + C_), 64, 0, stream>>>(in_v, in_g, out_v, out_g,
                                                  Win, Wout, lossac);
    cb2_kernel<<<dim3(K_), 64, 0, stream>>>(cb, CB2, invn);
    ze_kernel<<<dim3(64, 4, 4), 256, 0, stream>>>(x, Win, in_b, Zt, Z2);
    pmat_kernel<<<dim3(128, 8), 256, 0, stream>>>(cb, Wout, P);
    sim_kernel<<<dim3(8192), 256, 0, stream>>>(Z2, CB2, Part);
    argmax_kernel<<<dim3(4096), 256, 0, stream>>>(Part, Zt, cb, invn,
                                                  idx, out + OUT_IDX_OFF);
    loss_kernel<<<dim3(256), 256, 0, stream>>>(Zt, cb, idx, lossac);
    y_kernel<<<dim3(16, 4, 4), 256, 0, stream>>>(P, idx, out_b, out);
    fin_kernel<<<dim3(1), 64, 0, stream>>>(lossac, out + OUT_CB_OFF);
}

// Round 7
// 759.964 us; speedup vs baseline: 2.8758x; 2.8758x over previous
//
#include <hip/hip_runtime.h>
#include <math.h>

// Problem dims
#define N_ 4
#define C_ 512
#define L_ 4096
#define D_ 256
#define K_ 8192
#define NL_ 16384           // N_*L_

// d_out layout (float32 flat): y | code_index(as float) | cb_loss | cm_loss
#define OUT_IDX_OFF (N_*C_*L_)          // 8388608
#define OUT_CB_OFF  (OUT_IDX_OFF + NL_) // 8404992

// ws layout (float units).
#define WS_ZT   0                                  // Zt[16384][256] f32
#define WS_P    (WS_ZT + (size_t)NL_*D_)           // P[8192][512] f32
#define WS_Z2   (WS_P + (size_t)K_*C_)             // Z2[16384][512] bf16 (hi|lo row-major)
#define WS_CB2  (WS_Z2 + (size_t)NL_*D_)           // CB2F[512 c16][16 frag][64 lane][8] bf16
#define WS_PART (WS_CB2 + (size_t)K_*D_)           // Part[16384][4 ks][4] f32 top2 partials
#define WS_WIN  (WS_PART + (size_t)NL_*64*4)       // W_in[256][512]
#define WS_WOUT (WS_WIN + (size_t)D_*C_)           // W_out[512][256]
#define WS_INVN (WS_WOUT + (size_t)C_*D_)          // inv codebook norms [8192]
#define WS_IDX  (WS_INVN + (size_t)K_)             // idx[16384] (int)
#define WS_LOSS (WS_IDX + (size_t)NL_)             // loss accum [4]

typedef __bf16 bf16x8 __attribute__((ext_vector_type(8)));
typedef float  f32x4  __attribute__((ext_vector_type(4)));
typedef unsigned int u32;

__device__ __forceinline__ unsigned short f2bf(float f) {   // round-nearest-even
    u32 u = __float_as_uint(f);
    u32 r = (u + 0x7fffu + ((u >> 16) & 1u)) >> 16;
    return (unsigned short)r;
}
__device__ __forceinline__ float bf2f(unsigned short h) {
    return __uint_as_float(((u32)h) << 16);
}

__device__ __forceinline__ float waveReduceSum64(float s) {
    #pragma unroll
    for (int off = 32; off; off >>= 1) s += __shfl_xor(s, off, 64);
    return s;
}

// prefer (av,ai) over (bv,bi)?  larger value wins; tie -> smaller index
__device__ __forceinline__ bool pref(float av, int ai, float bv, int bi) {
    return (av > bv) || (av == bv && ai < bi);
}
// push candidate (wv,wi) into sorted top2 (v1,i1,v2,i2)
__device__ __forceinline__ void push2(float& v1, int& i1, float& v2, int& i2,
                                      float wv, int wi) {
    if (pref(wv, wi, v1, i1)) { v2 = v1; i2 = i1; v1 = wv; i1 = wi; }
    else if (pref(wv, wi, v2, i2)) { v2 = wv; i2 = wi; }
}

// ---------------------------------------------------------------------------
// prep: W_in = g*v/||v||, W_out likewise, zero loss accum.
// ---------------------------------------------------------------------------
__global__ __launch_bounds__(64) void prep_kernel(
    const float* __restrict__ in_v, const float* __restrict__ in_g,
    const float* __restrict__ out_v, const float* __restrict__ out_g,
    float* __restrict__ Win, float* __restrict__ Wout,
    float* __restrict__ lossacc)
{
    const int b = blockIdx.x;
    const int t = threadIdx.x;
    if (b == 0 && t < N_) lossacc[t] = 0.0f;
    if (b < D_) {
        const float* v = in_v + (size_t)b * C_;
        float4 a0 = *(const float4*)(v + t * 4);
        float4 a1 = *(const float4*)(v + 256 + t * 4);
        float s = a0.x*a0.x + a0.y*a0.y + a0.z*a0.z + a0.w*a0.w
                + a1.x*a1.x + a1.y*a1.y + a1.z*a1.z + a1.w*a1.w;
        s = waveReduceSum64(s);
        float scale = in_g[b] / sqrtf(s);
        float* w = Win + (size_t)b * C_;
        float4 o0, o1;
        o0.x=a0.x*scale; o0.y=a0.y*scale; o0.z=a0.z*scale; o0.w=a0.w*scale;
        o1.x=a1.x*scale; o1.y=a1.y*scale; o1.z=a1.z*scale; o1.w=a1.w*scale;
        *(float4*)(w + t*4) = o0;
        *(float4*)(w + 256 + t*4) = o1;
    } else {
        const int r = b - D_;
        const float* v = out_v + (size_t)r * D_;
        float4 a0 = *(const float4*)(v + t * 4);
        float s = a0.x*a0.x + a0.y*a0.y + a0.z*a0.z + a0.w*a0.w;
        s = waveReduceSum64(s);
        float scale = out_g[r] / sqrtf(s);
        float4 o0;
        o0.x=a0.x*scale; o0.y=a0.y*scale; o0.z=a0.z*scale; o0.w=a0.w*scale;
        *(float4*)(Wout + (size_t)r * D_ + t*4) = o0;
    }
}

// ---------------------------------------------------------------------------
// cb2: invn[k] = 1/max(||cb_k||,eps).  grid 8192 x 64
// ---------------------------------------------------------------------------
__global__ __launch_bounds__(64) void cb2_kernel(
    const float* __restrict__ cb, float* __restrict__ invn)
{
    const int k = blockIdx.x;
    const int t = threadIdx.x;
    float4 v = *(const float4*)(cb + (size_t)k * D_ + t * 4);
    float s = v.x*v.x + v.y*v.y + v.z*v.z + v.w*v.w;
    s = waveReduceSum64(s);
    if (t == 0) invn[k] = 1.0f / fmaxf(sqrtf(s), 1e-8f);
}

// ---------------------------------------------------------------------------
// cb2f: build B-fragment-ordered split codebook.
// Layout: frag(c16, kc) = 1 KB at ((c16*16 + kc)*64 lanes)*8 shorts.
// MFMA B-operand lane map (16x16x32): lane = (klocal>>3)*16 + n, j = klocal&7.
// kc 0..7: hi(d = kc*32 + klocal), scaled by invn; kc 8..15: lo of same d.
// grid 512 x 256.  thread t: kc = t>>4, n = t&15, covers d-range (kc&7)*32..+31.
// ---------------------------------------------------------------------------
__global__ __launch_bounds__(256) void cb2f_kernel(
    const float* __restrict__ cb, const float* __restrict__ invn,
    unsigned short* __restrict__ CB2F)
{
    const int c16 = blockIdx.x;
    const int t = threadIdx.x;
    const int kc = t >> 4, nl = t & 15;
    const int code = c16 * 16 + nl;
    const float inv = invn[code];
    const float* src = cb + (size_t)code * D_ + (kc & 7) * 32;
    unsigned short* dst = CB2F + ((size_t)(c16 * 16 + kc) * 64) * 8;
    #pragma unroll
    for (int lh = 0; lh < 4; ++lh) {
        float4 x0 = *(const float4*)(src + lh * 8);
        float4 x1 = *(const float4*)(src + lh * 8 + 4);
        float f[8] = {x0.x, x0.y, x0.z, x0.w, x1.x, x1.y, x1.z, x1.w};
        unsigned short o[8];
        #pragma unroll
        for (int j = 0; j < 8; ++j) {
            float v = f[j] * inv;
            unsigned short h = f2bf(v);
            o[j] = (kc < 8) ? h : f2bf(v - bf2f(h));
        }
        unsigned short* dp = dst + (lh * 16 + nl) * 8;
        *(ushort4*)&dp[0] = make_ushort4(o[0], o[1], o[2], o[3]);
        *(ushort4*)&dp[4] = make_ushort4(o[4], o[5], o[6], o[7]);
    }
}

// ---------------------------------------------------------------------------
// z_e GEMM: Zt[n*L+l][d] = sum_c x[n][c][l]*Win[d][c] + in_b[d]; also writes
// bf16 split Z2[row] = [hi | lo] row-major.
// ---------------------------------------------------------------------------
__global__ __launch_bounds__(256) void ze_kernel(
    const float* __restrict__ x, const float* __restrict__ Win,
    const float* __restrict__ inb, float* __restrict__ Zt,
    unsigned short* __restrict__ Z2)
{
    __shared__ float Al[2][16][64];   // x tile [c][l]
    __shared__ float Bl[2][16][68];   // Win tile [c][d] (padded)
    const int tid = threadIdx.x;
    const int ty = tid >> 4, tx = tid & 15;
    const int l0 = blockIdx.x * 64;
    const int d0 = blockIdx.y * 64;
    const int n  = blockIdx.z;
    const float* xn = x + (size_t)n * C_ * L_;

    const int ac = tid >> 4, alq = tid & 15;
    const int bd = tid >> 2, bq  = tid & 3;

    float acc[4][4];
    #pragma unroll
    for (int i = 0; i < 4; ++i)
        #pragma unroll
        for (int j = 0; j < 4; ++j) acc[i][j] = 0.0f;

    auto stage = [&](int cc, int buf) {
        float4 av = *(const float4*)(xn + (size_t)(cc*16 + ac) * L_ + l0 + alq*4);
        *(float4*)&Al[buf][ac][alq*4] = av;
        float4 bv = *(const float4*)(Win + (size_t)(d0 + bd) * C_ + cc*16 + bq*4);
        Bl[buf][bq*4+0][bd] = bv.x; Bl[buf][bq*4+1][bd] = bv.y;
        Bl[buf][bq*4+2][bd] = bv.z; Bl[buf][bq*4+3][bd] = bv.w;
    };

    stage(0, 0);
    for (int cc = 0; cc < 32; ++cc) {
        __syncthreads();
        if (cc + 1 < 32) stage(cc + 1, (cc + 1) & 1);
        const int buf = cc & 1;
        #pragma unroll
        for (int k = 0; k < 16; ++k) {
            float4 a = *(const float4*)&Al[buf][k][ty*4];
            float4 b = *(const float4*)&Bl[buf][k][tx*4];
            acc[0][0]=fmaf(a.x,b.x,acc[0][0]); acc[0][1]=fmaf(a.x,b.y,acc[0][1]);
            acc[0][2]=fmaf(a.x,b.z,acc[0][2]); acc[0][3]=fmaf(a.x,b.w,acc[0][3]);
            acc[1][0]=fmaf(a.y,b.x,acc[1][0]); acc[1][1]=fmaf(a.y,b.y,acc[1][1]);
            acc[1][2]=fmaf(a.y,b.z,acc[1][2]); acc[1][3]=fmaf(a.y,b.w,acc[1][3]);
            acc[2][0]=fmaf(a.z,b.x,acc[2][0]); acc[2][1]=fmaf(a.z,b.y,acc[2][1]);
            acc[2][2]=fmaf(a.z,b.z,acc[2][2]); acc[2][3]=fmaf(a.z,b.w,acc[2][3]);
            acc[3][0]=fmaf(a.w,b.x,acc[3][0]); acc[3][1]=fmaf(a.w,b.y,acc[3][1]);
            acc[3][2]=fmaf(a.w,b.z,acc[3][2]); acc[3][3]=fmaf(a.w,b.w,acc[3][3]);
        }
    }
    float4 bias = *(const float4*)(inb + d0 + tx*4);
    #pragma unroll
    for (int i = 0; i < 4; ++i) {
        float4 o;
        o.x = acc[i][0] + bias.x; o.y = acc[i][1] + bias.y;
        o.z = acc[i][2] + bias.z; o.w = acc[i][3] + bias.w;
        const size_t row = (size_t)(n*L_ + l0 + ty*4 + i);
        *(float4*)&Zt[row * D_ + d0 + tx*4] = o;
        ushort4 h, lo;
        h.x = f2bf(o.x); h.y = f2bf(o.y); h.z = f2bf(o.z); h.w = f2bf(o.w);
        lo.x = f2bf(o.x - bf2f(h.x)); lo.y = f2bf(o.y - bf2f(h.y));
        lo.z = f2bf(o.z - bf2f(h.z)); lo.w = f2bf(o.w - bf2f(h.w));
        *(ushort4*)&Z2[row * 512 + d0 + tx*4]       = h;
        *(ushort4*)&Z2[row * 512 + 256 + d0 + tx*4] = lo;
    }
}

// ---------------------------------------------------------------------------
// P GEMM: P[k][c] = sum_d cb[k][d] * Wout[c][d]    (8192 x 512 x 256)
// ---------------------------------------------------------------------------
__global__ __launch_bounds__(256) void pmat_kernel(
    const float* __restrict__ cb, const float* __restrict__ Wout,
    float* __restrict__ P)
{
    __shared__ float Al[2][16][68];
    __shared__ float Bl[2][16][68];
    const int tid = threadIdx.x;
    const int ty = tid >> 4, tx = tid & 15;
    const int k0 = blockIdx.x * 64;
    const int c0 = blockIdx.y * 64;
    const int ar = tid >> 2, aq = tid & 3;

    float acc[4][4];
    #pragma unroll
    for (int i = 0; i < 4; ++i)
        #pragma unroll
        for (int j = 0; j < 4; ++j) acc[i][j] = 0.0f;

    auto stage = [&](int dc, int buf) {
        float4 av = *(const float4*)(cb + (size_t)(k0 + ar) * D_ + dc*16 + aq*4);
        Al[buf][aq*4+0][ar] = av.x; Al[buf][aq*4+1][ar] = av.y;
        Al[buf][aq*4+2][ar] = av.z; Al[buf][aq*4+3][ar] = av.w;
        float4 bv = *(const float4*)(Wout + (size_t)(c0 + ar) * D_ + dc*16 + aq*4);
        Bl[buf][aq*4+0][ar] = bv.x; Bl[buf][aq*4+1][ar] = bv.y;
        Bl[buf][aq*4+2][ar] = bv.z; Bl[buf][aq*4+3][ar] = bv.w;
    };

    stage(0, 0);
    for (int dc = 0; dc < 16; ++dc) {
        __syncthreads();
        if (dc + 1 < 16) stage(dc + 1, (dc + 1) & 1);
        const int buf = dc & 1;
        #pragma unroll
        for (int k = 0; k < 16; ++k) {
            float4 a = *(const float4*)&Al[buf][k][ty*4];
            float4 b = *(const float4*)&Bl[buf][k][tx*4];
            acc[0][0]=fmaf(a.x,b.x,acc[0][0]); acc[0][1]=fmaf(a.x,b.y,acc[0][1]);
            acc[0][2]=fmaf(a.x,b.z,acc[0][2]); acc[0][3]=fmaf(a.x,b.w,acc[0][3]);
            acc[1][0]=fmaf(a.y,b.x,acc[1][0]); acc[1][1]=fmaf(a.y,b.y,acc[1][1]);
            acc[1][2]=fmaf(a.y,b.z,acc[1][2]); acc[1][3]=fmaf(a.y,b.w,acc[1][3]);
            acc[2][0]=fmaf(a.z,b.x,acc[2][0]); acc[2][1]=fmaf(a.z,b.y,acc[2][1]);
            acc[2][2]=fmaf(a.z,b.z,acc[2][2]); acc[2][3]=fmaf(a.z,b.w,acc[2][3]);
            acc[3][0]=fmaf(a.w,b.x,acc[3][0]); acc[3][1]=fmaf(a.w,b.y,acc[3][1]);
            acc[3][2]=fmaf(a.w,b.z,acc[3][2]); acc[3][3]=fmaf(a.w,b.w,acc[3][3]);
        }
    }
    #pragma unroll
    for (int i = 0; i < 4; ++i) {
        float4 o;
        o.x = acc[i][0]; o.y = acc[i][1]; o.z = acc[i][2]; o.w = acc[i][3];
        *(float4*)&P[(size_t)(k0 + ty*4 + i) * C_ + c0 + tx*4] = o;
    }
}

// ---------------------------------------------------------------------------
// sim (MFMA): barrier-free, LDS-free.  3-term bf16 split with shared factors:
// A768 = [hi|lo|hi] (16 distinct frags, 64 VGPRs, loaded ONCE per wave);
// B768 = [hi|hi|lo] (16 distinct frags per 16-code chunk, each one coalesced
// dwordx4 from fragment-ordered CB2F).  Per chunk: 16 loads + 24 MFMAs into
// 4 parallel acc chains + top2 update.  No __syncthreads in the K-loop.
// Wave = 16 rows x 2048 codes; block = 4 waves (64 rows) sharing the code
// stream (L1 reuse); ks = bid&3 is constant per XCD (round-robin dispatch)
// -> each XCD's 2 MB code slice stays L2-resident.
// grid 1024 x 256.  Part[row][ks] = (v1,i1,v2,i2).
// ---------------------------------------------------------------------------
__global__ __launch_bounds__(256, 2) void sim_kernel(
    const unsigned short* __restrict__ Z2, const unsigned short* __restrict__ CB2F,
    float* __restrict__ Part)
{
    const int tid = threadIdx.x;
    const int w = tid >> 6, l = tid & 63;
    const int bid = blockIdx.x;
    const int ks    = bid & 3;          // code range (constant per XCD)
    const int mtile = bid >> 2;         // 0..255
    const int m0 = mtile * 64 + w * 16;
    const int n0 = ks * 2048;

    // A fragments: lane holds A[m][k], m = l&15, klocal = (l>>4)*8 + j.
    // byte offset within row: kc*64 + (l>>4)*16 (+512 for lo).
    const char* Abase = (const char*)Z2 + (size_t)(m0 + (l & 15)) * 1024
                        + ((l >> 4) * 16);
    bf16x8 af[16];
    #pragma unroll
    for (int f = 0; f < 8; ++f) {
        af[f]     = *(const bf16x8*)(Abase + f * 64);          // hi
        af[f + 8] = *(const bf16x8*)(Abase + 512 + f * 64);    // lo
    }

    const char* Bbase = (const char*)CB2F + (size_t)(n0 >> 4) * 16384 + l * 16;

    float bv1[4], bv2[4]; int bi1[4], bi2[4];
    #pragma unroll
    for (int t = 0; t < 4; ++t) {
        bv1[t] = -3.0e38f; bv2[t] = -3.0e38f;
        bi1[t] = 0x7FFFFFFF; bi2[t] = 0x7FFFFFFF;
    }

    for (int c = 0; c < 128; ++c) {
        const char* p = Bbase + (size_t)c * 16384;
        bf16x8 bg[16];
        #pragma unroll
        for (int f = 0; f < 16; ++f)
            bg[f] = *(const bf16x8*)(p + f * 1024);

        f32x4 a0 = {0.f,0.f,0.f,0.f}, a1 = a0, a2 = a0, a3 = a0;
        #pragma unroll
        for (int f = 0; f < 8; f += 2) {
            a0 = __builtin_amdgcn_mfma_f32_16x16x32_bf16(af[f],   bg[f],   a0, 0,0,0); // hi*hi
            a1 = __builtin_amdgcn_mfma_f32_16x16x32_bf16(af[f+1], bg[f+1], a1, 0,0,0);
            a2 = __builtin_amdgcn_mfma_f32_16x16x32_bf16(af[f+8], bg[f],   a2, 0,0,0); // lo*hi
            a3 = __builtin_amdgcn_mfma_f32_16x16x32_bf16(af[f+9], bg[f+1], a3, 0,0,0);
            a0 = __builtin_amdgcn_mfma_f32_16x16x32_bf16(af[f],   bg[f+8], a0, 0,0,0); // hi*lo
            a1 = __builtin_amdgcn_mfma_f32_16x16x32_bf16(af[f+1], bg[f+9], a1, 0,0,0);
        }
        f32x4 s01 = a0 + a1, s23 = a2 + a3;
        f32x4 s = s01 + s23;

        const int colbase = n0 + c * 16 + (l & 15);
        #pragma unroll
        for (int t = 0; t < 4; ++t)
            push2(bv1[t], bi1[t], bv2[t], bi2[t], s[t], colbase);
    }

    // merge across the 16 col-lanes (xor masks 1,2,4,8); C/D layout:
    // col = lane&15, row = (lane>>4)*4 + reg
    #pragma unroll
    for (int t = 0; t < 4; ++t) {
        float v1 = bv1[t], v2 = bv2[t];
        int   i1 = bi1[t], i2 = bi2[t];
        #pragma unroll
        for (int mask = 1; mask < 16; mask <<= 1) {
            float ov1 = __shfl_xor(v1, mask, 64);
            int   oi1 = __shfl_xor(i1, mask, 64);
            float ov2 = __shfl_xor(v2, mask, 64);
            int   oi2 = __shfl_xor(i2, mask, 64);
            push2(v1, i1, v2, i2, ov1, oi1);
            push2(v1, i1, v2, i2, ov2, oi2);
        }
        if ((l & 15) == 0) {
            const int row = m0 + (l >> 4) * 4 + t;
            float4 o;
            o.x = v1; o.y = __int_as_float(i1);
            o.z = v2; o.w = __int_as_float(i2);
            *(float4*)&Part[((size_t)row * 4 + ks) * 4] = o;
        }
    }
}

// ---------------------------------------------------------------------------
// argmax reduce + exact fp32 recheck: merge 4 ks-partials/row -> top2,
// recompute both candidate dots in fp32, pick winner (tie -> smaller index).
// grid 4096 x 256 (wave per row).
// ---------------------------------------------------------------------------
__global__ __launch_bounds__(256) void argmax_kernel(
    const float* __restrict__ Part, const float* __restrict__ Zt,
    const float* __restrict__ cb, const float* __restrict__ invn,
    int* __restrict__ idxout, float* __restrict__ fidxout)
{
    const int w = threadIdx.x >> 6, l = threadIdx.x & 63;
    const int row = blockIdx.x * 4 + w;
    float v1 = -3.0e38f, v2 = -3.0e38f;
    int   i1 = 0x7FFFFFFF, i2 = 0x7FFFFFFF;
    if (l < 4) {
        float4 p = *(const float4*)&Part[((size_t)row * 4 + l) * 4];
        v1 = p.x; i1 = __float_as_int(p.y);
        v2 = p.z; i2 = __float_as_int(p.w);
    }
    #pragma unroll
    for (int mask = 1; mask < 4; mask <<= 1) {
        float ov1 = __shfl_xor(v1, mask, 64);
        int   oi1 = __shfl_xor(i1, mask, 64);
        float ov2 = __shfl_xor(v2, mask, 64);
        int   oi2 = __shfl_xor(i2, mask, 64);
        push2(v1, i1, v2, i2, ov1, oi1);
        push2(v1, i1, v2, i2, ov2, oi2);
    }
    // broadcast lane 0's top2 to all lanes
    v1 = __shfl(v1, 0, 64); i1 = __shfl(i1, 0, 64);
    v2 = __shfl(v2, 0, 64); i2 = __shfl(i2, 0, 64);
    // exact fp32 dots for the two candidates
    const float* z  = Zt + (size_t)row * D_;
    float4 zv = *(const float4*)(z + l*4);
    float4 a  = *(const float4*)(cb + (size_t)i1 * D_ + l*4);
    float4 b  = *(const float4*)(cb + (size_t)i2 * D_ + l*4);
    float s1 = zv.x*a.x + zv.y*a.y + zv.z*a.z + zv.w*a.w;
    float s2 = zv.x*b.x + zv.y*b.y + zv.z*b.z + zv.w*b.w;
    s1 = waveReduceSum64(s1);
    s2 = waveReduceSum64(s2);
    float e1 = s1 * invn[i1];
    float e2 = s2 * invn[i2];
    int win = (e2 > e1 || (e2 == e1 && i2 < i1)) ? i2 : i1;
    if (l == 0) { idxout[row] = win; fidxout[row] = (float)win; }
}

// ---------------------------------------------------------------------------
// losses: S[n] = sum_{l,d} (cb[idx[n,l]][d] - Zt[n*L+l][d])^2
// ---------------------------------------------------------------------------
__global__ __launch_bounds__(256) void loss_kernel(
    const float* __restrict__ Zt, const float* __restrict__ cb,
    const int* __restrict__ idx, float* __restrict__ lossacc)
{
    __shared__ float red[4];
    const int tid = threadIdx.x;
    const int r = blockIdx.x * 64 + (tid >> 2);
    const int q = tid & 3;
    const int n = r >> 12;
    const int code = idx[r];
    const float* zp = Zt + (size_t)r * D_ + q * 64;
    const float* cp = cb + (size_t)code * D_ + q * 64;
    float s = 0.0f;
    #pragma unroll
    for (int it = 0; it < 16; ++it) {
        float4 a = *(const float4*)(zp + it*4);
        float4 c = *(const float4*)(cp + it*4);
        float dx = c.x - a.x, dy = c.y - a.y, dz = c.z - a.z, dw = c.w - a.w;
        s += dx*dx + dy*dy + dz*dz + dw*dw;
    }
    s = waveReduceSum64(s);
    if ((tid & 63) == 0) red[tid >> 6] = s;
    __syncthreads();
    if (tid == 0) atomicAdd(&lossacc[n], red[0] + red[1] + red[2] + red[3]);
}

// ---------------------------------------------------------------------------
// y gather: y[n][c][l] = P[idx[n,l]][c] + out_b[c]
// ---------------------------------------------------------------------------
__global__ __launch_bounds__(256) void y_kernel(
    const float* __restrict__ P, const int* __restrict__ idx,
    const float* __restrict__ outb, float* __restrict__ y)
{
    __shared__ float bias[128];
    const int t = threadIdx.x;
    const int c0 = blockIdx.y * 128;
    const int n = blockIdx.z;
    const int l = blockIdx.x * 256 + t;
    if (t < 128) bias[t] = outb[c0 + t];
    __syncthreads();
    const int code = idx[n * L_ + l];
    const float* prow = P + (size_t)code * C_ + c0;
    float* yb = y + ((size_t)n * C_ + c0) * L_ + l;
    #pragma unroll 4
    for (int c = 0; c < 128; ++c) {
        yb[(size_t)c * L_] = prow[c] + bias[c];
    }
}

__global__ __launch_bounds__(64) void fin_kernel(
    const float* __restrict__ lossacc, float* __restrict__ out)
{
    const int t = threadIdx.x;
    if (t < 8) out[t] = lossacc[t & 3] * (1.0f / (float)(D_ * L_));
}

extern "C" void kernel_launch(void* const* d_in, const int* in_sizes, int n_in,
                              void* d_out, int out_size, void* d_ws, size_t ws_size,
                              hipStream_t stream) {
    (void)in_sizes; (void)n_in; (void)out_size; (void)ws_size;
    const float* x     = (const float*)d_in[0];
    const float* in_v  = (const float*)d_in[1];
    const float* in_g  = (const float*)d_in[2];
    const float* in_b  = (const float*)d_in[3];
    const float* out_v = (const float*)d_in[4];
    const float* out_g = (const float*)d_in[5];
    const float* out_b = (const float*)d_in[6];
    const float* cb    = (const float*)d_in[7];
    float* out = (float*)d_out;
    float* ws  = (float*)d_ws;

    float*          Zt     = ws + WS_ZT;
    float*          P      = ws + WS_P;
    unsigned short* Z2     = (unsigned short*)(ws + WS_Z2);
    unsigned short* CB2F   = (unsigned short*)(ws + WS_CB2);
    float*          Part   = ws + WS_PART;
    float*          Win    = ws + WS_WIN;
    float*          Wout   = ws + WS_WOUT;
    float*          invn   = ws + WS_INVN;
    int*            idx    = (int*)(ws + WS_IDX);
    float*          lossac = ws + WS_LOSS;

    prep_kernel<<<dim3(D_ + C_), 64, 0, stream>>>(in_v, in_g, out_v, out_g,
                                                  Win, Wout, lossac);
    cb2_kernel<<<dim3(K_), 64, 0, stream>>>(cb, invn);
    cb2f_kernel<<<dim3(512), 256, 0, stream>>>(cb, invn, CB2F);
    ze_kernel<<<dim3(64, 4, 4), 256, 0, stream>>>(x, Win, in_b, Zt, Z2);
    pmat_kernel<<<dim3(128, 8), 256, 0, stream>>>(cb, Wout, P);
    sim_kernel<<<dim3(1024), 256, 0, stream>>>(Z2, CB2F, Part);
    argmax_kernel<<<dim3(4096), 256, 0, stream>>>(Part, Zt, cb, invn,
                                                  idx, out + OUT_IDX_OFF);
    loss_kernel<<<dim3(256), 256, 0, stream>>>(Zt, cb, idx, lossac);
    y_kernel<<<dim3(16, 4, 4), 256, 0, stream>>>(P, idx, out_b, out);
    fin_kernel<<<dim3(1), 64, 0, stream>>>(lossac, out + OUT_CB_OFF);
}